// Round 14
// baseline (236.455 us; speedup 1.0000x reference)
//
#include <hip/hip_runtime.h>

constexpr int SL  = 2048;
constexpr int NB  = 2;
constexpr int NKV = 4;
constexpr int NH  = 16;
constexpr int DM  = 2048;

typedef unsigned short u16;
typedef unsigned int   u32;
typedef short s16x8 __attribute__((ext_vector_type(8)));
typedef float f32x4 __attribute__((ext_vector_type(4)));

__device__ inline u16 f2bf(float x) {
  union { float f; u32 u; } c; c.f = x;
  u32 r = c.u + 0x7fffu + ((c.u >> 16) & 1u);
  return (u16)(r >> 16);
}
__device__ inline float bf2f(u16 h) {
  union { u32 u; float f; } c; c.u = ((u32)h) << 16; return c.f;
}
__device__ inline u32 cvtpk_bf16(float lo, float hi) {
  u32 r;
  asm("v_cvt_pk_bf16_f32 %0, %1, %2" : "=v"(r) : "v"(lo), "v"(hi));
  return r;
}

__device__ inline void gload16(const void* g, void* l) {
  __builtin_amdgcn_global_load_lds((const __attribute__((address_space(1))) void*)g,
                                   (__attribute__((address_space(3))) void*)l, 16, 0, 0);
}

// ---------------- prep: cvt_x (blocks 0..4095) + 4x weight transpose ----------------
__global__ __launch_bounds__(256) void prep(const float* __restrict__ x,
                                            const float* __restrict__ Wq,
                                            const float* __restrict__ Wk,
                                            const float* __restrict__ Wv,
                                            const float* __restrict__ Wo,
                                            u16* __restrict__ xb,
                                            u16* __restrict__ WT,
                                            u16* __restrict__ WoT) {
  __shared__ float ld[64][65];
  int id = blockIdx.x;
  if (id < 4096) {
    long i = ((long)id * 256 + threadIdx.x) * 8;
    float4 a = *(const float4*)(x + i);
    float4 b = *(const float4*)(x + i + 4);
    uint4 ov;
    ov.x = (u32)f2bf(a.x) | ((u32)f2bf(a.y) << 16);
    ov.y = (u32)f2bf(a.z) | ((u32)f2bf(a.w) << 16);
    ov.z = (u32)f2bf(b.x) | ((u32)f2bf(b.y) << 16);
    ov.w = (u32)f2bf(b.z) | ((u32)f2bf(b.w) << 16);
    *(uint4*)(xb + i) = ov;
    return;
  }
  id -= 4096;
  const float* src; u16* dst; int N; long bx, by;
  const int K = 2048;
  if (id < 1024)      { src = Wq; dst = WT;                         N = 2048; bx = id & 31; by = id >> 5; }
  else if (id < 1280) { int j = id - 1024; src = Wk; dst = WT + (size_t)2048 * 2048; N = 512; bx = j & 7; by = j >> 3; }
  else if (id < 1536) { int j = id - 1280; src = Wv; dst = WT + (size_t)2560 * 2048; N = 512; bx = j & 7; by = j >> 3; }
  else                { int j = id - 1536; src = Wo; dst = WoT;                     N = 2048; bx = j & 31; by = j >> 5; }
  int tid = threadIdx.x;
  long c0 = bx * 64, r0 = by * 64;
#pragma unroll
  for (int i = 0; i < 4; ++i) {
    int e = tid + 256 * i;
    int r = e >> 4, cg = e & 15;
    float4 v = *(const float4*)(src + (r0 + r) * N + c0 + cg * 4);
    ld[r][cg * 4 + 0] = v.x;
    ld[r][cg * 4 + 1] = v.y;
    ld[r][cg * 4 + 2] = v.z;
    ld[r][cg * 4 + 3] = v.w;
  }
  __syncthreads();
#pragma unroll
  for (int i = 0; i < 4; ++i) {
    int e = tid + 256 * i;
    int cg = e & 15, rr = e >> 4;
    ushort4 o;
    o.x = f2bf(ld[cg * 4 + 0][rr]);
    o.y = f2bf(ld[cg * 4 + 1][rr]);
    o.z = f2bf(ld[cg * 4 + 2][rr]);
    o.w = f2bf(ld[cg * 4 + 3][rr]);
    *(ushort4*)(dst + (c0 + rr) * K + r0 + cg * 4) = o;
  }
}

// ---------------- GEMM1: 256x256 tile, 512 thr / 8 waves (2Mx4N), 8-phase counted-vmcnt ----------------
// T3+T4: 4 phases per K-tile, each {stage 1 half-tile, ds_read quadrant, barrier, 16 MFMA, barrier}.
// Half-tile stagger +5 -> vmcnt(4) once per K-tile (never 0 mid-loop). 128KB LDS, 2 waves/SIMD.
__global__ __launch_bounds__(512, 2) void gemm8p(const u16* __restrict__ A,
                                                 const u16* __restrict__ BT,
                                                 u16* __restrict__ Cb,
                                                 int M, int N, int K) {
  __shared__ __align__(16) char As[2][256 * 128];  // [slot][256 rows x 64 bf16], row stride 128B
  __shared__ __align__(16) char Bs[2][256 * 128];
  const int tid = threadIdx.x;
  const int lane = tid & 63;
  const int wid = tid >> 6;
  const int wm = wid >> 2, wn = wid & 3;   // 2M x 4N waves, per-wave C = 128x64
  const int lr = lane & 15, lg = lane >> 4;

  // T1 XCD-chunked remap (192 blocks, %8==0)
  const int flat = blockIdx.y * gridDim.x + blockIdx.x;
  const int chunk = (gridDim.x * gridDim.y) >> 3;
  const int nidx = (flat & 7) * chunk + (flat >> 3);
  const long bm = (long)(nidx / gridDim.y) * 256;
  const long bn = (long)(nidx % gridDim.y) * 256;

  f32x4 acc[8][4] = {};
  const int nt = K >> 6;

  // half-tile h: ktile=h>>2, type=h&3 (0=A0,1=A1,2=B0,3=B1), slot=(h>>2)&1
  auto stage_half = [&](int h) {
    const int t = h >> 2, ty = h & 3, slot = t & 1;
    const int kt0 = t << 6;
    const int rofs = (ty & 1) << 7;  // 0 or 128
    const u16* src = (ty < 2) ? (A + (bm + rofs) * (long)K) : (BT + (bn + rofs) * (long)K);
    char* dst = ((ty < 2) ? As[slot] : Bs[slot]) + (rofs << 7);  // rofs*128 bytes
#pragma unroll
    for (int i = 0; i < 2; ++i) {
      int c = tid + 512 * i;
      int row = c >> 3;
      int slotcol = (c & 7) << 4;
      int gs = slotcol ^ ((row & 7) << 4);
      gload16(src + (long)row * K + kt0 + (gs >> 1), dst + c * 16);
    }
  };

  // prologue: halves 0..4 (tile 0 complete + A0 of tile 1)
  for (int h = 0; h < 5; ++h) stage_half(h);

#pragma unroll 1
  for (int t = 0; t < nt; ++t) {
    const int S = t & 1;
    const int hb = 4 * t + 5;
    const int hmax = 4 * nt;
    s16x8 af[4][2], bf[2][2];

    auto rdA = [&](int m, int kk) -> s16x8 {
      int row = wm * 128 + m * 16 + lr;
      int col = (kk * 32 + lg * 8) * 2;
      return *(const s16x8*)(As[S] + row * 128 + (col ^ ((row & 7) << 4)));
    };
    auto rdB = [&](int n, int kk) -> s16x8 {
      int row = wn * 64 + n * 16 + lr;
      int col = (kk * 32 + lg * 8) * 2;
      return *(const s16x8*)(Bs[S] + row * 128 + (col ^ ((row & 7) << 4)));
    };

    // ---- phase 0: quadrant m0..3 x n0..1 (new K-tile: vmcnt+barrier BEFORE ds_read)
    if (hb < hmax) stage_half(hb);
    if (t + 1 < nt) asm volatile("s_waitcnt vmcnt(4)" ::: "memory");
    else            asm volatile("s_waitcnt vmcnt(0)" ::: "memory");
    __builtin_amdgcn_s_barrier();
#pragma unroll
    for (int m = 0; m < 4; ++m) { af[m][0] = rdA(m, 0); af[m][1] = rdA(m, 1); }
#pragma unroll
    for (int n = 0; n < 2; ++n) { bf[n][0] = rdB(n, 0); bf[n][1] = rdB(n, 1); }
    __builtin_amdgcn_s_setprio(1);
#pragma unroll
    for (int kk = 0; kk < 2; ++kk)
#pragma unroll
      for (int m = 0; m < 4; ++m)
#pragma unroll
        for (int n = 0; n < 2; ++n)
          acc[m][n] = __builtin_amdgcn_mfma_f32_16x16x32_bf16(af[m][kk], bf[n][kk], acc[m][n], 0, 0, 0);
    __builtin_amdgcn_s_setprio(0);
    __builtin_amdgcn_s_barrier();

    // ---- phase 1: m0..3 x n2..3 (af reuse)
    if (hb + 1 < hmax) stage_half(hb + 1);
#pragma unroll
    for (int n = 0; n < 2; ++n) { bf[n][0] = rdB(n + 2, 0); bf[n][1] = rdB(n + 2, 1); }
    __builtin_amdgcn_s_barrier();
    __builtin_amdgcn_s_setprio(1);
#pragma unroll
    for (int kk = 0; kk < 2; ++kk)
#pragma unroll
      for (int m = 0; m < 4; ++m)
#pragma unroll
        for (int n = 0; n < 2; ++n)
          acc[m][n + 2] = __builtin_amdgcn_mfma_f32_16x16x32_bf16(af[m][kk], bf[n][kk], acc[m][n + 2], 0, 0, 0);
    __builtin_amdgcn_s_setprio(0);
    __builtin_amdgcn_s_barrier();

    // ---- phase 2: m4..7 x n2..3 (bf reuse)
    if (hb + 2 < hmax) stage_half(hb + 2);
#pragma unroll
    for (int m = 0; m < 4; ++m) { af[m][0] = rdA(m + 4, 0); af[m][1] = rdA(m + 4, 1); }
    __builtin_amdgcn_s_barrier();
    __builtin_amdgcn_s_setprio(1);
#pragma unroll
    for (int kk = 0; kk < 2; ++kk)
#pragma unroll
      for (int m = 0; m < 4; ++m)
#pragma unroll
        for (int n = 0; n < 2; ++n)
          acc[m + 4][n + 2] = __builtin_amdgcn_mfma_f32_16x16x32_bf16(af[m][kk], bf[n][kk], acc[m + 4][n + 2], 0, 0, 0);
    __builtin_amdgcn_s_setprio(0);
    __builtin_amdgcn_s_barrier();

    // ---- phase 3: m4..7 x n0..1 (af reuse; reads B only -> A0(t+2) stage is safe)
    if (hb + 3 < hmax) stage_half(hb + 3);
#pragma unroll
    for (int n = 0; n < 2; ++n) { bf[n][0] = rdB(n, 0); bf[n][1] = rdB(n, 1); }
    __builtin_amdgcn_s_barrier();
    __builtin_amdgcn_s_setprio(1);
#pragma unroll
    for (int kk = 0; kk < 2; ++kk)
#pragma unroll
      for (int m = 0; m < 4; ++m)
#pragma unroll
        for (int n = 0; n < 2; ++n)
          acc[m + 4][n] = __builtin_amdgcn_mfma_f32_16x16x32_bf16(af[m][kk], bf[n][kk], acc[m + 4][n], 0, 0, 0);
    __builtin_amdgcn_s_setprio(0);
    __builtin_amdgcn_s_barrier();
  }

#pragma unroll
  for (int m = 0; m < 8; ++m)
#pragma unroll
    for (int n = 0; n < 4; ++n) {
      long row = bm + wm * 128 + m * 16 + lg * 4;
      long col = bn + wn * 64 + n * 16 + lr;
#pragma unroll
      for (int r = 0; r < 4; ++r)
        Cb[(row + r) * N + col] = f2bf(acc[m][n][r]);
    }
}

// ---------------- GEMM2 (round-13 known-good): 256x128, 4 waves, single-buffer, T1 swizzle ----------------
__global__ __launch_bounds__(256, 2) void gemm_bt(const u16* __restrict__ A,
                                                  const u16* __restrict__ BT,
                                                  float* __restrict__ Cf,
                                                  int M, int N, int K) {
  __shared__ __align__(16) char As[256 * 128];
  __shared__ __align__(16) char Bs[128 * 128];
  const int tid = threadIdx.x;
  const int lane = tid & 63;
  const int w = tid >> 6;
  const int wm = w >> 1, wn = w & 1;
  const int lr = lane & 15, lg = lane >> 4;

  const int flat = blockIdx.y * gridDim.x + blockIdx.x;
  const int chunk = (gridDim.x * gridDim.y) >> 3;
  const int nidx = (flat & 7) * chunk + (flat >> 3);
  const int bxl = nidx / gridDim.y;
  const int byl = nidx % gridDim.y;
  const long bm = (long)bxl * 256;
  const long bn = (long)byl * 128;

  f32x4 acc[8][4] = {};

  const int nt = K >> 6;
#pragma unroll 1
  for (int ti = 0; ti < nt; ++ti) {
    const int kt0 = ti << 6;
#pragma unroll
    for (int i = 0; i < 8; ++i) {
      int c = tid + 256 * i;
      int row = c >> 3;
      int slot = (c & 7) << 4;
      int gs = slot ^ ((row & 7) << 4);
      gload16(A + (bm + row) * K + kt0 + (gs >> 1), As + c * 16);
    }
#pragma unroll
    for (int i = 0; i < 4; ++i) {
      int c = tid + 256 * i;
      int row = c >> 3;
      int slot = (c & 7) << 4;
      int gs = slot ^ ((row & 7) << 4);
      gload16(BT + (bn + row) * K + kt0 + (gs >> 1), Bs + c * 16);
    }
    __syncthreads();

    __builtin_amdgcn_s_setprio(1);
#pragma unroll
    for (int kk = 0; kk < 2; ++kk) {
      int colB = (kk * 32 + lg * 8) * 2;
      s16x8 af[8], bfv[4];
#pragma unroll
      for (int m = 0; m < 8; ++m) {
        int row = wm * 128 + m * 16 + lr;
        af[m] = *(const s16x8*)(As + row * 128 + (colB ^ ((row & 7) << 4)));
      }
#pragma unroll
      for (int n = 0; n < 4; ++n) {
        int row = wn * 64 + n * 16 + lr;
        bfv[n] = *(const s16x8*)(Bs + row * 128 + (colB ^ ((row & 7) << 4)));
      }
#pragma unroll
      for (int m = 0; m < 8; ++m)
#pragma unroll
        for (int n = 0; n < 4; ++n)
          acc[m][n] = __builtin_amdgcn_mfma_f32_16x16x32_bf16(af[m], bfv[n], acc[m][n], 0, 0, 0);
    }
    __builtin_amdgcn_s_setprio(0);
    __syncthreads();
  }

#pragma unroll
  for (int m = 0; m < 8; ++m)
#pragma unroll
    for (int n = 0; n < 4; ++n) {
      long row = bm + wm * 128 + m * 16 + lg * 4;
      long col = bn + wn * 64 + n * 16 + lr;
#pragma unroll
      for (int r = 0; r < 4; ++r)
        Cf[(row + r) * N + col] = acc[m][n][r];
    }
}

// ---------------- postqkv: normrope (blocks 0..4095, inline trig) + vtrans ----------------
__global__ __launch_bounds__(256) void postqkv(const u16* __restrict__ qkv,
                                               const float* __restrict__ qg,
                                               u16* __restrict__ qb, u16* __restrict__ kb,
                                               u16* __restrict__ vt) {
  __shared__ u16 ldt[64][136];
  int id = blockIdx.x;
  int tid = threadIdx.x;
  if (id < 4096) {
    int token = id;
    int b = token >> 11, t = token & (SL - 1);
    int lane = tid & 63, w = tid >> 6;
    const u16* row = qkv + (long)token * 3072;
    float inv = __expf(-(float)lane * (9.210340371976184f / 64.0f));
    float ang = (float)t * inv;
    float c = cosf(ang), s = sinf(ang);
    for (int slot = w; slot < 20; slot += 4) {
      const u16* p = row + slot * 128;
      float v0 = bf2f(p[lane]), v1 = bf2f(p[lane + 64]);
      float ss = v0 * v0 + v1 * v1;
      for (int m = 1; m < 64; m <<= 1) ss += __shfl_xor(ss, m);
      float rms = rsqrtf(ss * (1.0f / 128.0f) + 1.1920929e-07f);
      v0 *= rms; v1 *= rms;
      float o0 =  v0 * c + v1 * s;
      float o1 = -v0 * s + v1 * c;
      u16* dst;
      if (slot < 16) {
        float g = qg[slot] * 0.08838834764831845f * 1.4426950408889634f;  // 1/sqrt(HD) * log2e
        o0 *= g; o1 *= g;
        dst = qb + ((long)(b * NH + slot) * SL + t) * 128;
      } else {
        dst = kb + ((long)(b * NKV + (slot - 16)) * SL + t) * 128;
      }
      dst[lane] = f2bf(o0);
      dst[lane + 64] = f2bf(o1);
    }
    return;
  }
  int blk = id - 4096;
  int tt = blk & 31, kvb = blk >> 5;
  const u16* src = qkv + (long)(((kvb >> 2) * SL) + tt * 64) * 3072 + 2560 + (kvb & 3) * 128;
#pragma unroll
  for (int i = 0; i < 4; ++i) {
    int e = tid + 256 * i;
    int r = e >> 4, dg = e & 15;
    uint4 v = *(const uint4*)(src + (long)r * 3072 + dg * 8);
    *(uint4*)(&ldt[r][dg * 8]) = v;
  }
  __syncthreads();
  u16* dst = vt + (long)kvb * 128 * SL + tt * 64;
#pragma unroll
  for (int i = 0; i < 8; ++i) {
    int e = tid + 256 * i;
    int rg = e & 15, d = e >> 4;
    ushort4 o;
    o.x = ldt[rg * 4 + 0][d];
    o.y = ldt[rg * 4 + 1][d];
    o.z = ldt[rg * 4 + 2][d];
    o.w = ldt[rg * 4 + 3][d];
    *(ushort4*)(dst + (long)d * SL + rg * 4) = o;
  }
}

// ---------------- flash attention (causal, GQA) + fused v-projection epilogue ----------------
__global__ __launch_bounds__(256) void attn(const u16* __restrict__ qb, const u16* __restrict__ kb,
                                            const u16* __restrict__ vt, const float* __restrict__ qg,
                                            const u16* __restrict__ qkvb, u16* __restrict__ yb) {
  __shared__ __align__(16) char Ks[2][64 * 256];
  __shared__ __align__(16) char Vs[2][128 * 128];
  __shared__ __align__(16) char Ps[64 * 128];
  const int tid = threadIdx.x, lane = tid & 63, w = tid >> 6;

  const int flat = blockIdx.y * 16 + blockIdx.x;
  const int nidx = (flat & 7) * 64 + (flat >> 3);
  const int pairIdx = nidx & 15;
  const int bh = nidx >> 4;

  const int b = bh >> 4, h = bh & 15;
  const int kvh = h >> 2;
  const int lr = lane & 15, lg = lane >> 4;

  const float Ms = 16.3223f * fabsf(qg[h]);

  const u16* kbase = kb + (long)(b * NKV + kvh) * SL * 128;
  const u16* vbase = vt + (long)(b * NKV + kvh) * 128 * SL;

#pragma unroll 1
  for (int pass = 0; pass < 2; ++pass) {
    const int qblk = pass ? 31 - pairIdx : pairIdx;
    const int ntile = qblk + 1;

    const u16* qp = qb + ((long)bh * SL + qblk * 64 + w * 16 + lr) * 128;
    s16x8 qf[4];
#pragma unroll
    for (int kk = 0; kk < 4; ++kk) qf[kk] = *(const s16x8*)(qp + kk * 32 + lg * 8);

    f32x4 acc[8] = {};
    float lsum[4] = {0.f, 0.f, 0.f, 0.f};

#pragma unroll
    for (int i = 0; i < 4; ++i) {
      int c = tid + 256 * i;
      int row = c >> 4, slot = (c & 15) << 4;
      gload16(kbase + (long)row * 128 + ((slot ^ ((row & 15) << 4)) >> 1), Ks[0] + c * 16);
    }
#pragma unroll
    for (int i = 0; i < 4; ++i) {
      int c = tid + 256 * i;
      int row = c >> 3, slot = (c & 7) << 4;
      gload16(vbase + (long)row * SL + ((slot ^ ((row & 7) << 4)) >> 1), Vs[0] + c * 16);
    }

#pragma unroll 1
    for (int kt = 0; kt < ntile; ++kt) {
      const int cur = kt & 1;
      if (kt + 1 < ntile) {
        const int nx = cur ^ 1;
#pragma unroll
        for (int i = 0; i < 4; ++i) {
          int c = tid + 256 * i;
          int row = c >> 4, slot = (c & 15) << 4;
          gload16(kbase + (long)((kt + 1) * 64 + row) * 128 + ((slot ^ ((row & 15) << 4)) >> 1),
                  Ks[nx] + c * 16);
        }
#pragma unroll
        for (int i = 0; i < 4; ++i) {
          int c = tid + 256 * i;
          int row = c >> 3, slot = (c & 7) << 4;
          gload16(vbase + (long)row * SL + (kt + 1) * 64 + ((slot ^ ((row & 7) << 4)) >> 1),
                  Vs[nx] + c * 16);
        }
        asm volatile("s_waitcnt vmcnt(8)" ::: "memory");
      } else {
        asm volatile("s_waitcnt vmcnt(0)" ::: "memory");
      }
      __builtin_amdgcn_s_barrier();

      f32x4 sv[4];
      __builtin_amdgcn_s_setprio(1);
#pragma unroll
      for (int n = 0; n < 4; ++n) {
        f32x4 z = {0.f, 0.f, 0.f, 0.f};
#pragma unroll
        for (int kk = 0; kk < 4; ++kk) {
          int row = n * 16 + lr;
          s16x8 kf = *(const s16x8*)(Ks[cur] + row * 256 + (((kk * 32 + lg * 8) * 2) ^ ((row & 15) << 4)));
          z = __builtin_amdgcn_mfma_f32_16x16x32_bf16(qf[kk], kf, z, 0, 0, 0);
        }
        sv[n] = z;
      }
      __builtin_amdgcn_s_setprio(0);

      if (kt == qblk) {
#pragma unroll
        for (int n = 0; n < 4; ++n)
#pragma unroll
          for (int r = 0; r < 4; ++r) {
            int colA = n * 16 + lr;
            int rowA = w * 16 + lg * 4 + r;
            if (colA > rowA) sv[n][r] = -1e30f;
          }
      }
#pragma unroll
      for (int n = 0; n < 4; ++n)
#pragma unroll
        for (int r = 0; r < 4; ++r) {
          float p = __builtin_amdgcn_exp2f(sv[n][r] - Ms);
          sv[n][r] = p;
          lsum[r] += p;
        }
#pragma unroll
      for (int n = 0; n < 4; ++n) {
        u32 pk0 = cvtpk_bf16(sv[n][0], sv[n][1]);
        u32 pk1 = cvtpk_bf16(sv[n][2], sv[n][3]);
        int row = w * 16 + lg * 4;
        int colB = (n * 16 + lr) * 2;
        *(u16*)(Ps + (row + 0) * 128 + (colB ^ (((row + 0) & 7) << 4))) = (u16)pk0;
        *(u16*)(Ps + (row + 1) * 128 + (colB ^ (((row + 1) & 7) << 4))) = (u16)(pk0 >> 16);
        *(u16*)(Ps + (row + 2) * 128 + (colB ^ (((row + 2) & 7) << 4))) = (u16)pk1;
        *(u16*)(Ps + (row + 3) * 128 + (colB ^ (((row + 3) & 7) << 4))) = (u16)(pk1 >> 16);
      }
      __builtin_amdgcn_s_setprio(1);
#pragma unroll
      for (int kk = 0; kk < 2; ++kk) {
        int prow = w * 16 + lr;
        s16x8 pa = *(const s16x8*)(Ps + prow * 128 + (((kk * 32 + lg * 8) * 2) ^ ((prow & 7) << 4)));
#pragma unroll
        for (int n = 0; n < 8; ++n) {
          int vrow = n * 16 + lr;
          s16x8 vf = *(const s16x8*)(Vs[cur] + vrow * 128 + (((kk * 32 + lg * 8) * 2) ^ ((vrow & 7) << 4)));
          acc[n] = __builtin_amdgcn_mfma_f32_16x16x32_bf16(pa, vf, acc[n], 0, 0, 0);
        }
      }
      __builtin_amdgcn_s_setprio(0);
      __builtin_amdgcn_s_barrier();
    }

    float inv_l[4];
#pragma unroll
    for (int r = 0; r < 4; ++r) {
      float v = lsum[r];
      v += __shfl_xor(v, 1);
      v += __shfl_xor(v, 2);
      v += __shfl_xor(v, 4);
      v += __shfl_xor(v, 8);
      inv_l[r] = 1.0f / v;
    }
    const int row0 = qblk * 64 + w * 16 + lg * 4;
    float vv[8][4];
    float ssq[4], dot[4];
#pragma unroll
    for (int r = 0; r < 4; ++r) {
      const u16* pr = qkvb + ((long)(b * SL + row0 + r) * 3072) + 2560 + kvh * 128;
      float sq = 0.f;
#pragma unroll
      for (int n = 0; n < 8; ++n) {
        float t = bf2f(pr[n * 16 + lr]);
        vv[n][r] = t;
        sq += t * t;
      }
      ssq[r] = sq;
    }
#pragma unroll
    for (int r = 0; r < 4; ++r) {
      float sq = ssq[r];
      sq += __shfl_xor(sq, 1);
      sq += __shfl_xor(sq, 2);
      sq += __shfl_xor(sq, 4);
      sq += __shfl_xor(sq, 8);
      ssq[r] = sq;
      float d = 0.f;
#pragma unroll
      for (int n = 0; n < 8; ++n) {
        float yn = acc[n][r] * inv_l[r];
        acc[n][r] = yn;
        d += yn * vv[n][r];
      }
      dot[r] = d;
    }
#pragma unroll
    for (int r = 0; r < 4; ++r) {
      float d = dot[r];
      d += __shfl_xor(d, 1);
      d += __shfl_xor(d, 2);
      d += __shfl_xor(d, 4);
      d += __shfl_xor(d, 8);
      dot[r] = d / fmaxf(ssq[r], 1e-24f);
    }
    u16* yp = yb + ((long)(b * SL + row0)) * DM + h * 128;
#pragma unroll
    for (int n = 0; n < 8; ++n)
#pragma unroll
      for (int r = 0; r < 4; ++r)
        yp[(long)r * DM + n * 16 + lr] = f2bf(acc[n][r] - dot[r] * vv[n][r]);
  }
}

extern "C" void kernel_launch(void* const* d_in, const int* in_sizes, int n_in,
                              void* d_out, int out_size, void* d_ws, size_t ws_size,
                              hipStream_t stream) {
  const float* x  = (const float*)d_in[0];
  const float* Wq = (const float*)d_in[1];
  const float* Wk = (const float*)d_in[2];
  const float* Wv = (const float*)d_in[3];
  const float* Wo = (const float*)d_in[4];
  const float* qg = (const float*)d_in[5];
  float* out = (float*)d_out;

  char* p = (char*)d_ws;
  u16* xb    = (u16*)p;   p += (size_t)4096 * 2048 * 2;
  u16* WT    = (u16*)p;   p += (size_t)3072 * 2048 * 2;
  u16* WoT   = (u16*)p;   p += (size_t)2048 * 2048 * 2;
  u16* qkvb  = (u16*)p;   p += (size_t)4096 * 3072 * 2;
  u16* qbuf  = (u16*)p;   p += (size_t)NB * NH * SL * 128 * 2;
  u16* kbuf  = (u16*)p;   p += (size_t)NB * NKV * SL * 128 * 2;
  u16* vtb   = (u16*)p;   p += (size_t)NB * NKV * 128 * SL * 2;
  u16* yb = xb;  // alias: xb dead after qkv GEMM

  prep<<<6656, 256, 0, stream>>>(x, Wq, Wk, Wv, Wo, xb, WT, WoT);
  gemm8p<<<dim3(16, 12), 512, 0, stream>>>(xb, WT, qkvb, 4096, 3072, 2048);
  postqkv<<<4352, 256, 0, stream>>>(qkvb, qg, qbuf, kbuf, vtb);
  attn<<<dim3(16, 32), 256, 0, stream>>>(qbuf, kbuf, vtb, qg, qkvb, yb);
  gemm_bt<<<dim3(16, 16), 256, 0, stream>>>(yb, WoT, out, 4096, 2048, 2048);
}

// Round 15
// 201.880 us; speedup vs baseline: 1.1713x; 1.1713x over previous
//
#include <hip/hip_runtime.h>

constexpr int SL  = 2048;
constexpr int NB  = 2;
constexpr int NKV = 4;
constexpr int NH  = 16;
constexpr int DM  = 2048;

typedef unsigned short u16;
typedef unsigned int   u32;
typedef short s16x8 __attribute__((ext_vector_type(8)));
typedef float f32x4 __attribute__((ext_vector_type(4)));

__device__ inline u16 f2bf(float x) {
  union { float f; u32 u; } c; c.f = x;
  u32 r = c.u + 0x7fffu + ((c.u >> 16) & 1u);
  return (u16)(r >> 16);
}
__device__ inline float bf2f(u16 h) {
  union { u32 u; float f; } c; c.u = ((u32)h) << 16; return c.f;
}
__device__ inline u32 cvtpk_bf16(float lo, float hi) {
  u32 r;
  asm("v_cvt_pk_bf16_f32 %0, %1, %2" : "=v"(r) : "v"(lo), "v"(hi));
  return r;
}

__device__ inline void gload16(const void* g, void* l) {
  __builtin_amdgcn_global_load_lds((const __attribute__((address_space(1))) void*)g,
                                   (__attribute__((address_space(3))) void*)l, 16, 0, 0);
}

// ---------------- prep: cvt_x (blocks 0..4095) + 4x weight transpose ----------------
__global__ __launch_bounds__(256) void prep(const float* __restrict__ x,
                                            const float* __restrict__ Wq,
                                            const float* __restrict__ Wk,
                                            const float* __restrict__ Wv,
                                            const float* __restrict__ Wo,
                                            u16* __restrict__ xb,
                                            u16* __restrict__ WT,
                                            u16* __restrict__ WoT) {
  __shared__ float ld[64][65];
  int id = blockIdx.x;
  if (id < 4096) {
    long i = ((long)id * 256 + threadIdx.x) * 8;
    float4 a = *(const float4*)(x + i);
    float4 b = *(const float4*)(x + i + 4);
    uint4 ov;
    ov.x = (u32)f2bf(a.x) | ((u32)f2bf(a.y) << 16);
    ov.y = (u32)f2bf(a.z) | ((u32)f2bf(a.w) << 16);
    ov.z = (u32)f2bf(b.x) | ((u32)f2bf(b.y) << 16);
    ov.w = (u32)f2bf(b.z) | ((u32)f2bf(b.w) << 16);
    *(uint4*)(xb + i) = ov;
    return;
  }
  id -= 4096;
  const float* src; u16* dst; int N; long bx, by;
  const int K = 2048;
  if (id < 1024)      { src = Wq; dst = WT;                         N = 2048; bx = id & 31; by = id >> 5; }
  else if (id < 1280) { int j = id - 1024; src = Wk; dst = WT + (size_t)2048 * 2048; N = 512; bx = j & 7; by = j >> 3; }
  else if (id < 1536) { int j = id - 1280; src = Wv; dst = WT + (size_t)2560 * 2048; N = 512; bx = j & 7; by = j >> 3; }
  else                { int j = id - 1536; src = Wo; dst = WoT;                     N = 2048; bx = j & 31; by = j >> 5; }
  int tid = threadIdx.x;
  long c0 = bx * 64, r0 = by * 64;
#pragma unroll
  for (int i = 0; i < 4; ++i) {
    int e = tid + 256 * i;
    int r = e >> 4, cg = e & 15;
    float4 v = *(const float4*)(src + (r0 + r) * N + c0 + cg * 4);
    ld[r][cg * 4 + 0] = v.x;
    ld[r][cg * 4 + 1] = v.y;
    ld[r][cg * 4 + 2] = v.z;
    ld[r][cg * 4 + 3] = v.w;
  }
  __syncthreads();
#pragma unroll
  for (int i = 0; i < 4; ++i) {
    int e = tid + 256 * i;
    int cg = e & 15, rr = e >> 4;
    ushort4 o;
    o.x = f2bf(ld[cg * 4 + 0][rr]);
    o.y = f2bf(ld[cg * 4 + 1][rr]);
    o.z = f2bf(ld[cg * 4 + 2][rr]);
    o.w = f2bf(ld[cg * 4 + 3][rr]);
    *(ushort4*)(dst + (c0 + rr) * K + r0 + cg * 4) = o;
  }
}

// ---------------- GEMM: 256x128 tile, 4 waves of 128x64, BK=64, single-buffer ----------------
// T1 XCD-chunked block swizzle (nwg % 8 == 0 at both call sites).
template <int BF16OUT>
__global__ __launch_bounds__(256, 2) void gemm_bt(const u16* __restrict__ A,
                                                  const u16* __restrict__ BT,
                                                  float* __restrict__ Cf,
                                                  u16* __restrict__ Cb,
                                                  int M, int N, int K) {
  __shared__ __align__(16) char As[256 * 128];
  __shared__ __align__(16) char Bs[128 * 128];
  const int tid = threadIdx.x;
  const int lane = tid & 63;
  const int w = tid >> 6;
  const int wm = w >> 1, wn = w & 1;
  const int lr = lane & 15, lg = lane >> 4;

  const int flat = blockIdx.y * gridDim.x + blockIdx.x;
  const int chunk = (gridDim.x * gridDim.y) >> 3;
  const int nidx = (flat & 7) * chunk + (flat >> 3);
  const int bxl = nidx / gridDim.y;
  const int byl = nidx % gridDim.y;
  const long bm = (long)bxl * 256;
  const long bn = (long)byl * 128;

  f32x4 acc[8][4] = {};

  const int nt = K >> 6;
#pragma unroll 1
  for (int ti = 0; ti < nt; ++ti) {
    const int kt0 = ti << 6;
#pragma unroll
    for (int i = 0; i < 8; ++i) {
      int c = tid + 256 * i;
      int row = c >> 3;
      int slot = (c & 7) << 4;
      int gs = slot ^ ((row & 7) << 4);
      gload16(A + (bm + row) * K + kt0 + (gs >> 1), As + c * 16);
    }
#pragma unroll
    for (int i = 0; i < 4; ++i) {
      int c = tid + 256 * i;
      int row = c >> 3;
      int slot = (c & 7) << 4;
      int gs = slot ^ ((row & 7) << 4);
      gload16(BT + (bn + row) * K + kt0 + (gs >> 1), Bs + c * 16);
    }
    __syncthreads();

    __builtin_amdgcn_s_setprio(1);
#pragma unroll
    for (int kk = 0; kk < 2; ++kk) {
      int colB = (kk * 32 + lg * 8) * 2;
      s16x8 af[8], bfv[4];
#pragma unroll
      for (int m = 0; m < 8; ++m) {
        int row = wm * 128 + m * 16 + lr;
        af[m] = *(const s16x8*)(As + row * 128 + (colB ^ ((row & 7) << 4)));
      }
#pragma unroll
      for (int n = 0; n < 4; ++n) {
        int row = wn * 64 + n * 16 + lr;
        bfv[n] = *(const s16x8*)(Bs + row * 128 + (colB ^ ((row & 7) << 4)));
      }
#pragma unroll
      for (int m = 0; m < 8; ++m)
#pragma unroll
        for (int n = 0; n < 4; ++n)
          acc[m][n] = __builtin_amdgcn_mfma_f32_16x16x32_bf16(af[m], bfv[n], acc[m][n], 0, 0, 0);
    }
    __builtin_amdgcn_s_setprio(0);
    __syncthreads();
  }

#pragma unroll
  for (int m = 0; m < 8; ++m)
#pragma unroll
    for (int n = 0; n < 4; ++n) {
      long row = bm + wm * 128 + m * 16 + lg * 4;
      long col = bn + wn * 64 + n * 16 + lr;
#pragma unroll
      for (int r = 0; r < 4; ++r) {
        if (BF16OUT)
          Cb[(row + r) * N + col] = f2bf(acc[m][n][r]);
        else
          Cf[(row + r) * N + col] = acc[m][n][r];
      }
    }
}

// ---------------- postqkv: normrope (blocks 0..4095, inline trig) + vtrans ----------------
__global__ __launch_bounds__(256) void postqkv(const u16* __restrict__ qkv,
                                               const float* __restrict__ qg,
                                               u16* __restrict__ qb, u16* __restrict__ kb,
                                               u16* __restrict__ vt) {
  __shared__ u16 ldt[64][136];
  int id = blockIdx.x;
  int tid = threadIdx.x;
  if (id < 4096) {
    int token = id;
    int b = token >> 11, t = token & (SL - 1);
    int lane = tid & 63, w = tid >> 6;
    const u16* row = qkv + (long)token * 3072;
    float inv = __expf(-(float)lane * (9.210340371976184f / 64.0f));
    float ang = (float)t * inv;
    float c = cosf(ang), s = sinf(ang);
    for (int slot = w; slot < 20; slot += 4) {
      const u16* p = row + slot * 128;
      float v0 = bf2f(p[lane]), v1 = bf2f(p[lane + 64]);
      float ss = v0 * v0 + v1 * v1;
      for (int m = 1; m < 64; m <<= 1) ss += __shfl_xor(ss, m);
      float rms = rsqrtf(ss * (1.0f / 128.0f) + 1.1920929e-07f);
      v0 *= rms; v1 *= rms;
      float o0 =  v0 * c + v1 * s;
      float o1 = -v0 * s + v1 * c;
      u16* dst;
      if (slot < 16) {
        float g = qg[slot] * 0.08838834764831845f * 1.4426950408889634f;  // 1/sqrt(HD) * log2e
        o0 *= g; o1 *= g;
        dst = qb + ((long)(b * NH + slot) * SL + t) * 128;
      } else {
        dst = kb + ((long)(b * NKV + (slot - 16)) * SL + t) * 128;
      }
      dst[lane] = f2bf(o0);
      dst[lane + 64] = f2bf(o1);
    }
    return;
  }
  int blk = id - 4096;
  int tt = blk & 31, kvb = blk >> 5;
  const u16* src = qkv + (long)(((kvb >> 2) * SL) + tt * 64) * 3072 + 2560 + (kvb & 3) * 128;
#pragma unroll
  for (int i = 0; i < 4; ++i) {
    int e = tid + 256 * i;
    int r = e >> 4, dg = e & 15;
    uint4 v = *(const uint4*)(src + (long)r * 3072 + dg * 8);
    *(uint4*)(&ldt[r][dg * 8]) = v;
  }
  __syncthreads();
  u16* dst = vt + (long)kvb * 128 * SL + tt * 64;
#pragma unroll
  for (int i = 0; i < 8; ++i) {
    int e = tid + 256 * i;
    int rg = e & 15, d = e >> 4;
    ushort4 o;
    o.x = ldt[rg * 4 + 0][d];
    o.y = ldt[rg * 4 + 1][d];
    o.z = ldt[rg * 4 + 2][d];
    o.w = ldt[rg * 4 + 3][d];
    *(ushort4*)(dst + (long)d * SL + rg * 4) = o;
  }
}

// ---------------- flash attention (causal, GQA) + fused v-projection epilogue ----------------
// T1 XCD-chunked swizzle: XCD j owns bh in [4j, 4j+4) = exactly one (b,kvh) KV panel.
__global__ __launch_bounds__(256) void attn(const u16* __restrict__ qb, const u16* __restrict__ kb,
                                            const u16* __restrict__ vt, const float* __restrict__ qg,
                                            const u16* __restrict__ qkvb, u16* __restrict__ yb) {
  __shared__ __align__(16) char Ks[2][64 * 256];
  __shared__ __align__(16) char Vs[2][128 * 128];
  __shared__ __align__(16) char Ps[64 * 128];
  const int tid = threadIdx.x, lane = tid & 63, w = tid >> 6;

  const int flat = blockIdx.y * 16 + blockIdx.x;
  const int nidx = (flat & 7) * 64 + (flat >> 3);
  const int pairIdx = nidx & 15;
  const int bh = nidx >> 4;

  const int b = bh >> 4, h = bh & 15;
  const int kvh = h >> 2;
  const int lr = lane & 15, lg = lane >> 4;

  const float Ms = 16.3223f * fabsf(qg[h]);

  const u16* kbase = kb + (long)(b * NKV + kvh) * SL * 128;
  const u16* vbase = vt + (long)(b * NKV + kvh) * 128 * SL;

#pragma unroll 1
  for (int pass = 0; pass < 2; ++pass) {
    const int qblk = pass ? 31 - pairIdx : pairIdx;
    const int ntile = qblk + 1;

    const u16* qp = qb + ((long)bh * SL + qblk * 64 + w * 16 + lr) * 128;
    s16x8 qf[4];
#pragma unroll
    for (int kk = 0; kk < 4; ++kk) qf[kk] = *(const s16x8*)(qp + kk * 32 + lg * 8);

    f32x4 acc[8] = {};
    float lsum[4] = {0.f, 0.f, 0.f, 0.f};

#pragma unroll
    for (int i = 0; i < 4; ++i) {
      int c = tid + 256 * i;
      int row = c >> 4, slot = (c & 15) << 4;
      gload16(kbase + (long)row * 128 + ((slot ^ ((row & 15) << 4)) >> 1), Ks[0] + c * 16);
    }
#pragma unroll
    for (int i = 0; i < 4; ++i) {
      int c = tid + 256 * i;
      int row = c >> 3, slot = (c & 7) << 4;
      gload16(vbase + (long)row * SL + ((slot ^ ((row & 7) << 4)) >> 1), Vs[0] + c * 16);
    }

#pragma unroll 1
    for (int kt = 0; kt < ntile; ++kt) {
      const int cur = kt & 1;
      if (kt + 1 < ntile) {
        const int nx = cur ^ 1;
#pragma unroll
        for (int i = 0; i < 4; ++i) {
          int c = tid + 256 * i;
          int row = c >> 4, slot = (c & 15) << 4;
          gload16(kbase + (long)((kt + 1) * 64 + row) * 128 + ((slot ^ ((row & 15) << 4)) >> 1),
                  Ks[nx] + c * 16);
        }
#pragma unroll
        for (int i = 0; i < 4; ++i) {
          int c = tid + 256 * i;
          int row = c >> 3, slot = (c & 7) << 4;
          gload16(vbase + (long)row * SL + (kt + 1) * 64 + ((slot ^ ((row & 7) << 4)) >> 1),
                  Vs[nx] + c * 16);
        }
        asm volatile("s_waitcnt vmcnt(8)" ::: "memory");
      } else {
        asm volatile("s_waitcnt vmcnt(0)" ::: "memory");
      }
      __builtin_amdgcn_s_barrier();

      f32x4 sv[4];
      __builtin_amdgcn_s_setprio(1);
#pragma unroll
      for (int n = 0; n < 4; ++n) {
        f32x4 z = {0.f, 0.f, 0.f, 0.f};
#pragma unroll
        for (int kk = 0; kk < 4; ++kk) {
          int row = n * 16 + lr;
          s16x8 kf = *(const s16x8*)(Ks[cur] + row * 256 + (((kk * 32 + lg * 8) * 2) ^ ((row & 15) << 4)));
          z = __builtin_amdgcn_mfma_f32_16x16x32_bf16(qf[kk], kf, z, 0, 0, 0);
        }
        sv[n] = z;
      }
      __builtin_amdgcn_s_setprio(0);

      if (kt == qblk) {
#pragma unroll
        for (int n = 0; n < 4; ++n)
#pragma unroll
          for (int r = 0; r < 4; ++r) {
            int colA = n * 16 + lr;
            int rowA = w * 16 + lg * 4 + r;
            if (colA > rowA) sv[n][r] = -1e30f;
          }
      }
#pragma unroll
      for (int n = 0; n < 4; ++n)
#pragma unroll
        for (int r = 0; r < 4; ++r) {
          float p = __builtin_amdgcn_exp2f(sv[n][r] - Ms);
          sv[n][r] = p;
          lsum[r] += p;
        }
#pragma unroll
      for (int n = 0; n < 4; ++n) {
        u32 pk0 = cvtpk_bf16(sv[n][0], sv[n][1]);
        u32 pk1 = cvtpk_bf16(sv[n][2], sv[n][3]);
        int row = w * 16 + lg * 4;
        int colB = (n * 16 + lr) * 2;
        *(u16*)(Ps + (row + 0) * 128 + (colB ^ (((row + 0) & 7) << 4))) = (u16)pk0;
        *(u16*)(Ps + (row + 1) * 128 + (colB ^ (((row + 1) & 7) << 4))) = (u16)(pk0 >> 16);
        *(u16*)(Ps + (row + 2) * 128 + (colB ^ (((row + 2) & 7) << 4))) = (u16)pk1;
        *(u16*)(Ps + (row + 3) * 128 + (colB ^ (((row + 3) & 7) << 4))) = (u16)(pk1 >> 16);
      }
      __builtin_amdgcn_s_setprio(1);
#pragma unroll
      for (int kk = 0; kk < 2; ++kk) {
        int prow = w * 16 + lr;
        s16x8 pa = *(const s16x8*)(Ps + prow * 128 + (((kk * 32 + lg * 8) * 2) ^ ((prow & 7) << 4)));
#pragma unroll
        for (int n = 0; n < 8; ++n) {
          int vrow = n * 16 + lr;
          s16x8 vf = *(const s16x8*)(Vs[cur] + vrow * 128 + (((kk * 32 + lg * 8) * 2) ^ ((vrow & 7) << 4)));
          acc[n] = __builtin_amdgcn_mfma_f32_16x16x32_bf16(pa, vf, acc[n], 0, 0, 0);
        }
      }
      __builtin_amdgcn_s_setprio(0);
      __builtin_amdgcn_s_barrier();
    }

    float inv_l[4];
#pragma unroll
    for (int r = 0; r < 4; ++r) {
      float v = lsum[r];
      v += __shfl_xor(v, 1);
      v += __shfl_xor(v, 2);
      v += __shfl_xor(v, 4);
      v += __shfl_xor(v, 8);
      inv_l[r] = 1.0f / v;
    }
    const int row0 = qblk * 64 + w * 16 + lg * 4;
    float vv[8][4];
    float ssq[4], dot[4];
#pragma unroll
    for (int r = 0; r < 4; ++r) {
      const u16* pr = qkvb + ((long)(b * SL + row0 + r) * 3072) + 2560 + kvh * 128;
      float sq = 0.f;
#pragma unroll
      for (int n = 0; n < 8; ++n) {
        float t = bf2f(pr[n * 16 + lr]);
        vv[n][r] = t;
        sq += t * t;
      }
      ssq[r] = sq;
    }
#pragma unroll
    for (int r = 0; r < 4; ++r) {
      float sq = ssq[r];
      sq += __shfl_xor(sq, 1);
      sq += __shfl_xor(sq, 2);
      sq += __shfl_xor(sq, 4);
      sq += __shfl_xor(sq, 8);
      ssq[r] = sq;
      float d = 0.f;
#pragma unroll
      for (int n = 0; n < 8; ++n) {
        float yn = acc[n][r] * inv_l[r];
        acc[n][r] = yn;
        d += yn * vv[n][r];
      }
      dot[r] = d;
    }
#pragma unroll
    for (int r = 0; r < 4; ++r) {
      float d = dot[r];
      d += __shfl_xor(d, 1);
      d += __shfl_xor(d, 2);
      d += __shfl_xor(d, 4);
      d += __shfl_xor(d, 8);
      dot[r] = d / fmaxf(ssq[r], 1e-24f);
    }
    u16* yp = yb + ((long)(b * SL + row0)) * DM + h * 128;
#pragma unroll
    for (int n = 0; n < 8; ++n)
#pragma unroll
      for (int r = 0; r < 4; ++r)
        yp[(long)r * DM + n * 16 + lr] = f2bf(acc[n][r] - dot[r] * vv[n][r]);
  }
}

extern "C" void kernel_launch(void* const* d_in, const int* in_sizes, int n_in,
                              void* d_out, int out_size, void* d_ws, size_t ws_size,
                              hipStream_t stream) {
  const float* x  = (const float*)d_in[0];
  const float* Wq = (const float*)d_in[1];
  const float* Wk = (const float*)d_in[2];
  const float* Wv = (const float*)d_in[3];
  const float* Wo = (const float*)d_in[4];
  const float* qg = (const float*)d_in[5];
  float* out = (float*)d_out;

  char* p = (char*)d_ws;
  u16* xb    = (u16*)p;   p += (size_t)4096 * 2048 * 2;
  u16* WT    = (u16*)p;   p += (size_t)3072 * 2048 * 2;
  u16* WoT   = (u16*)p;   p += (size_t)2048 * 2048 * 2;
  u16* qkvb  = (u16*)p;   p += (size_t)4096 * 3072 * 2;
  u16* qbuf  = (u16*)p;   p += (size_t)NB * NH * SL * 128 * 2;
  u16* kbuf  = (u16*)p;   p += (size_t)NB * NKV * SL * 128 * 2;
  u16* vtb   = (u16*)p;   p += (size_t)NB * NKV * 128 * SL * 2;
  u16* yb = xb;  // alias: xb dead after qkv GEMM

  prep<<<6656, 256, 0, stream>>>(x, Wq, Wk, Wv, Wo, xb, WT, WoT);
  gemm_bt<1><<<dim3(16, 24), 256, 0, stream>>>(xb, WT, nullptr, qkvb, 4096, 3072, 2048);
  postqkv<<<4352, 256, 0, stream>>>(qkvb, qg, qbuf, kbuf, vtb);
  attn<<<dim3(16, 32), 256, 0, stream>>>(qbuf, kbuf, vtb, qg, qkvb, yb);
  gemm_bt<0><<<dim3(16, 16), 256, 0, stream>>>(yb, WoT, out, nullptr, 4096, 2048, 2048);
}

// Round 16
// 200.978 us; speedup vs baseline: 1.1765x; 1.0045x over previous
//
#include <hip/hip_runtime.h>

constexpr int SL  = 2048;
constexpr int NB  = 2;
constexpr int NKV = 4;
constexpr int NH  = 16;
constexpr int DM  = 2048;

typedef unsigned short u16;
typedef unsigned int   u32;
typedef short s16x8 __attribute__((ext_vector_type(8)));
typedef float f32x4 __attribute__((ext_vector_type(4)));

__device__ inline u16 f2bf(float x) {
  union { float f; u32 u; } c; c.f = x;
  u32 r = c.u + 0x7fffu + ((c.u >> 16) & 1u);
  return (u16)(r >> 16);
}
__device__ inline float bf2f(u16 h) {
  union { u32 u; float f; } c; c.u = ((u32)h) << 16; return c.f;
}
__device__ inline u32 cvtpk_bf16(float lo, float hi) {
  u32 r;
  asm("v_cvt_pk_bf16_f32 %0, %1, %2" : "=v"(r) : "v"(lo), "v"(hi));
  return r;
}

__device__ inline void gload16(const void* g, void* l) {
  __builtin_amdgcn_global_load_lds((const __attribute__((address_space(1))) void*)g,
                                   (__attribute__((address_space(3))) void*)l, 16, 0, 0);
}

// ---------------- prep: cvt_x (blocks 0..4095) + 4x weight transpose ----------------
__global__ __launch_bounds__(256) void prep(const float* __restrict__ x,
                                            const float* __restrict__ Wq,
                                            const float* __restrict__ Wk,
                                            const float* __restrict__ Wv,
                                            const float* __restrict__ Wo,
                                            u16* __restrict__ xb,
                                            u16* __restrict__ WT,
                                            u16* __restrict__ WoT) {
  __shared__ float ld[64][65];
  int id = blockIdx.x;
  if (id < 4096) {
    long i = ((long)id * 256 + threadIdx.x) * 8;
    float4 a = *(const float4*)(x + i);
    float4 b = *(const float4*)(x + i + 4);
    uint4 ov;
    ov.x = (u32)f2bf(a.x) | ((u32)f2bf(a.y) << 16);
    ov.y = (u32)f2bf(a.z) | ((u32)f2bf(a.w) << 16);
    ov.z = (u32)f2bf(b.x) | ((u32)f2bf(b.y) << 16);
    ov.w = (u32)f2bf(b.z) | ((u32)f2bf(b.w) << 16);
    *(uint4*)(xb + i) = ov;
    return;
  }
  id -= 4096;
  const float* src; u16* dst; int N; long bx, by;
  const int K = 2048;
  if (id < 1024)      { src = Wq; dst = WT;                         N = 2048; bx = id & 31; by = id >> 5; }
  else if (id < 1280) { int j = id - 1024; src = Wk; dst = WT + (size_t)2048 * 2048; N = 512; bx = j & 7; by = j >> 3; }
  else if (id < 1536) { int j = id - 1280; src = Wv; dst = WT + (size_t)2560 * 2048; N = 512; bx = j & 7; by = j >> 3; }
  else                { int j = id - 1536; src = Wo; dst = WoT;                     N = 2048; bx = j & 31; by = j >> 5; }
  int tid = threadIdx.x;
  long c0 = bx * 64, r0 = by * 64;
#pragma unroll
  for (int i = 0; i < 4; ++i) {
    int e = tid + 256 * i;
    int r = e >> 4, cg = e & 15;
    float4 v = *(const float4*)(src + (r0 + r) * N + c0 + cg * 4);
    ld[r][cg * 4 + 0] = v.x;
    ld[r][cg * 4 + 1] = v.y;
    ld[r][cg * 4 + 2] = v.z;
    ld[r][cg * 4 + 3] = v.w;
  }
  __syncthreads();
#pragma unroll
  for (int i = 0; i < 4; ++i) {
    int e = tid + 256 * i;
    int cg = e & 15, rr = e >> 4;
    ushort4 o;
    o.x = f2bf(ld[cg * 4 + 0][rr]);
    o.y = f2bf(ld[cg * 4 + 1][rr]);
    o.z = f2bf(ld[cg * 4 + 2][rr]);
    o.w = f2bf(ld[cg * 4 + 3][rr]);
    *(ushort4*)(dst + (c0 + rr) * K + r0 + cg * 4) = o;
  }
}

// ---------------- GEMM: 256x128 tile, 4 waves of 128x64, BK=64, single-buffer ----------------
// T1 XCD-chunked block swizzle (nwg % 8 == 0 at both call sites).
template <int BF16OUT>
__global__ __launch_bounds__(256, 2) void gemm_bt(const u16* __restrict__ A,
                                                  const u16* __restrict__ BT,
                                                  float* __restrict__ Cf,
                                                  u16* __restrict__ Cb,
                                                  int M, int N, int K) {
  __shared__ __align__(16) char As[256 * 128];
  __shared__ __align__(16) char Bs[128 * 128];
  const int tid = threadIdx.x;
  const int lane = tid & 63;
  const int w = tid >> 6;
  const int wm = w >> 1, wn = w & 1;
  const int lr = lane & 15, lg = lane >> 4;

  const int flat = blockIdx.y * gridDim.x + blockIdx.x;
  const int chunk = (gridDim.x * gridDim.y) >> 3;
  const int nidx = (flat & 7) * chunk + (flat >> 3);
  const int bxl = nidx / gridDim.y;
  const int byl = nidx % gridDim.y;
  const long bm = (long)bxl * 256;
  const long bn = (long)byl * 128;

  f32x4 acc[8][4] = {};

  const int nt = K >> 6;
#pragma unroll 1
  for (int ti = 0; ti < nt; ++ti) {
    const int kt0 = ti << 6;
#pragma unroll
    for (int i = 0; i < 8; ++i) {
      int c = tid + 256 * i;
      int row = c >> 3;
      int slot = (c & 7) << 4;
      int gs = slot ^ ((row & 7) << 4);
      gload16(A + (bm + row) * K + kt0 + (gs >> 1), As + c * 16);
    }
#pragma unroll
    for (int i = 0; i < 4; ++i) {
      int c = tid + 256 * i;
      int row = c >> 3;
      int slot = (c & 7) << 4;
      int gs = slot ^ ((row & 7) << 4);
      gload16(BT + (bn + row) * K + kt0 + (gs >> 1), Bs + c * 16);
    }
    __syncthreads();

    __builtin_amdgcn_s_setprio(1);
#pragma unroll
    for (int kk = 0; kk < 2; ++kk) {
      int colB = (kk * 32 + lg * 8) * 2;
      s16x8 af[8], bfv[4];
#pragma unroll
      for (int m = 0; m < 8; ++m) {
        int row = wm * 128 + m * 16 + lr;
        af[m] = *(const s16x8*)(As + row * 128 + (colB ^ ((row & 7) << 4)));
      }
#pragma unroll
      for (int n = 0; n < 4; ++n) {
        int row = wn * 64 + n * 16 + lr;
        bfv[n] = *(const s16x8*)(Bs + row * 128 + (colB ^ ((row & 7) << 4)));
      }
#pragma unroll
      for (int m = 0; m < 8; ++m)
#pragma unroll
        for (int n = 0; n < 4; ++n)
          acc[m][n] = __builtin_amdgcn_mfma_f32_16x16x32_bf16(af[m], bfv[n], acc[m][n], 0, 0, 0);
    }
    __builtin_amdgcn_s_setprio(0);
    __syncthreads();
  }

#pragma unroll
  for (int m = 0; m < 8; ++m)
#pragma unroll
    for (int n = 0; n < 4; ++n) {
      long row = bm + wm * 128 + m * 16 + lg * 4;
      long col = bn + wn * 64 + n * 16 + lr;
#pragma unroll
      for (int r = 0; r < 4; ++r) {
        if (BF16OUT)
          Cb[(row + r) * N + col] = f2bf(acc[m][n][r]);
        else
          Cf[(row + r) * N + col] = acc[m][n][r];
      }
    }
}

// ---------------- postqkv: normrope (blocks 0..4095, fast HW trig) + vtrans ----------------
// __sinf/__cosf -> v_sin_f32/v_cos_f32 (revolutions + HW fract). Worst-case arg 2047 rad:
// rev-conversion rounding ~2e-4 abs error, an order below bf16 quantization (~4e-3).
__global__ __launch_bounds__(256) void postqkv(const u16* __restrict__ qkv,
                                               const float* __restrict__ qg,
                                               u16* __restrict__ qb, u16* __restrict__ kb,
                                               u16* __restrict__ vt) {
  __shared__ u16 ldt[64][136];
  int id = blockIdx.x;
  int tid = threadIdx.x;
  if (id < 4096) {
    int token = id;
    int b = token >> 11, t = token & (SL - 1);
    int lane = tid & 63, w = tid >> 6;
    const u16* row = qkv + (long)token * 3072;
    float inv = __expf(-(float)lane * (9.210340371976184f / 64.0f));
    float ang = (float)t * inv;
    float c = __cosf(ang), s = __sinf(ang);
    for (int slot = w; slot < 20; slot += 4) {
      const u16* p = row + slot * 128;
      float v0 = bf2f(p[lane]), v1 = bf2f(p[lane + 64]);
      float ss = v0 * v0 + v1 * v1;
      for (int m = 1; m < 64; m <<= 1) ss += __shfl_xor(ss, m);
      float rms = rsqrtf(ss * (1.0f / 128.0f) + 1.1920929e-07f);
      v0 *= rms; v1 *= rms;
      float o0 =  v0 * c + v1 * s;
      float o1 = -v0 * s + v1 * c;
      u16* dst;
      if (slot < 16) {
        float g = qg[slot] * 0.08838834764831845f * 1.4426950408889634f;  // 1/sqrt(HD) * log2e
        o0 *= g; o1 *= g;
        dst = qb + ((long)(b * NH + slot) * SL + t) * 128;
      } else {
        dst = kb + ((long)(b * NKV + (slot - 16)) * SL + t) * 128;
      }
      dst[lane] = f2bf(o0);
      dst[lane + 64] = f2bf(o1);
    }
    return;
  }
  int blk = id - 4096;
  int tt = blk & 31, kvb = blk >> 5;
  const u16* src = qkv + (long)(((kvb >> 2) * SL) + tt * 64) * 3072 + 2560 + (kvb & 3) * 128;
#pragma unroll
  for (int i = 0; i < 4; ++i) {
    int e = tid + 256 * i;
    int r = e >> 4, dg = e & 15;
    uint4 v = *(const uint4*)(src + (long)r * 3072 + dg * 8);
    *(uint4*)(&ldt[r][dg * 8]) = v;
  }
  __syncthreads();
  u16* dst = vt + (long)kvb * 128 * SL + tt * 64;
#pragma unroll
  for (int i = 0; i < 8; ++i) {
    int e = tid + 256 * i;
    int rg = e & 15, d = e >> 4;
    ushort4 o;
    o.x = ldt[rg * 4 + 0][d];
    o.y = ldt[rg * 4 + 1][d];
    o.z = ldt[rg * 4 + 2][d];
    o.w = ldt[rg * 4 + 3][d];
    *(ushort4*)(dst + (long)d * SL + rg * 4) = o;
  }
}

// ---------------- flash attention (causal, GQA) + fused v-projection epilogue ----------------
// T1 XCD-chunked swizzle: XCD j owns bh in [4j, 4j+4) = exactly one (b,kvh) KV panel.
__global__ __launch_bounds__(256) void attn(const u16* __restrict__ qb, const u16* __restrict__ kb,
                                            const u16* __restrict__ vt, const float* __restrict__ qg,
                                            const u16* __restrict__ qkvb, u16* __restrict__ yb) {
  __shared__ __align__(16) char Ks[2][64 * 256];
  __shared__ __align__(16) char Vs[2][128 * 128];
  __shared__ __align__(16) char Ps[64 * 128];
  const int tid = threadIdx.x, lane = tid & 63, w = tid >> 6;

  const int flat = blockIdx.y * 16 + blockIdx.x;
  const int nidx = (flat & 7) * 64 + (flat >> 3);
  const int pairIdx = nidx & 15;
  const int bh = nidx >> 4;

  const int b = bh >> 4, h = bh & 15;
  const int kvh = h >> 2;
  const int lr = lane & 15, lg = lane >> 4;

  const float Ms = 16.3223f * fabsf(qg[h]);

  const u16* kbase = kb + (long)(b * NKV + kvh) * SL * 128;
  const u16* vbase = vt + (long)(b * NKV + kvh) * 128 * SL;

#pragma unroll 1
  for (int pass = 0; pass < 2; ++pass) {
    const int qblk = pass ? 31 - pairIdx : pairIdx;
    const int ntile = qblk + 1;

    const u16* qp = qb + ((long)bh * SL + qblk * 64 + w * 16 + lr) * 128;
    s16x8 qf[4];
#pragma unroll
    for (int kk = 0; kk < 4; ++kk) qf[kk] = *(const s16x8*)(qp + kk * 32 + lg * 8);

    f32x4 acc[8] = {};
    float lsum[4] = {0.f, 0.f, 0.f, 0.f};

#pragma unroll
    for (int i = 0; i < 4; ++i) {
      int c = tid + 256 * i;
      int row = c >> 4, slot = (c & 15) << 4;
      gload16(kbase + (long)row * 128 + ((slot ^ ((row & 15) << 4)) >> 1), Ks[0] + c * 16);
    }
#pragma unroll
    for (int i = 0; i < 4; ++i) {
      int c = tid + 256 * i;
      int row = c >> 3, slot = (c & 7) << 4;
      gload16(vbase + (long)row * SL + ((slot ^ ((row & 7) << 4)) >> 1), Vs[0] + c * 16);
    }

#pragma unroll 1
    for (int kt = 0; kt < ntile; ++kt) {
      const int cur = kt & 1;
      if (kt + 1 < ntile) {
        const int nx = cur ^ 1;
#pragma unroll
        for (int i = 0; i < 4; ++i) {
          int c = tid + 256 * i;
          int row = c >> 4, slot = (c & 15) << 4;
          gload16(kbase + (long)((kt + 1) * 64 + row) * 128 + ((slot ^ ((row & 15) << 4)) >> 1),
                  Ks[nx] + c * 16);
        }
#pragma unroll
        for (int i = 0; i < 4; ++i) {
          int c = tid + 256 * i;
          int row = c >> 3, slot = (c & 7) << 4;
          gload16(vbase + (long)row * SL + (kt + 1) * 64 + ((slot ^ ((row & 7) << 4)) >> 1),
                  Vs[nx] + c * 16);
        }
        asm volatile("s_waitcnt vmcnt(8)" ::: "memory");
      } else {
        asm volatile("s_waitcnt vmcnt(0)" ::: "memory");
      }
      __builtin_amdgcn_s_barrier();

      f32x4 sv[4];
      __builtin_amdgcn_s_setprio(1);
#pragma unroll
      for (int n = 0; n < 4; ++n) {
        f32x4 z = {0.f, 0.f, 0.f, 0.f};
#pragma unroll
        for (int kk = 0; kk < 4; ++kk) {
          int row = n * 16 + lr;
          s16x8 kf = *(const s16x8*)(Ks[cur] + row * 256 + (((kk * 32 + lg * 8) * 2) ^ ((row & 15) << 4)));
          z = __builtin_amdgcn_mfma_f32_16x16x32_bf16(qf[kk], kf, z, 0, 0, 0);
        }
        sv[n] = z;
      }
      __builtin_amdgcn_s_setprio(0);

      if (kt == qblk) {
#pragma unroll
        for (int n = 0; n < 4; ++n)
#pragma unroll
          for (int r = 0; r < 4; ++r) {
            int colA = n * 16 + lr;
            int rowA = w * 16 + lg * 4 + r;
            if (colA > rowA) sv[n][r] = -1e30f;
          }
      }
#pragma unroll
      for (int n = 0; n < 4; ++n)
#pragma unroll
        for (int r = 0; r < 4; ++r) {
          float p = __builtin_amdgcn_exp2f(sv[n][r] - Ms);
          sv[n][r] = p;
          lsum[r] += p;
        }
#pragma unroll
      for (int n = 0; n < 4; ++n) {
        u32 pk0 = cvtpk_bf16(sv[n][0], sv[n][1]);
        u32 pk1 = cvtpk_bf16(sv[n][2], sv[n][3]);
        int row = w * 16 + lg * 4;
        int colB = (n * 16 + lr) * 2;
        *(u16*)(Ps + (row + 0) * 128 + (colB ^ (((row + 0) & 7) << 4))) = (u16)pk0;
        *(u16*)(Ps + (row + 1) * 128 + (colB ^ (((row + 1) & 7) << 4))) = (u16)(pk0 >> 16);
        *(u16*)(Ps + (row + 2) * 128 + (colB ^ (((row + 2) & 7) << 4))) = (u16)pk1;
        *(u16*)(Ps + (row + 3) * 128 + (colB ^ (((row + 3) & 7) << 4))) = (u16)(pk1 >> 16);
      }
      __builtin_amdgcn_s_setprio(1);
#pragma unroll
      for (int kk = 0; kk < 2; ++kk) {
        int prow = w * 16 + lr;
        s16x8 pa = *(const s16x8*)(Ps + prow * 128 + (((kk * 32 + lg * 8) * 2) ^ ((prow & 7) << 4)));
#pragma unroll
        for (int n = 0; n < 8; ++n) {
          int vrow = n * 16 + lr;
          s16x8 vf = *(const s16x8*)(Vs[cur] + vrow * 128 + (((kk * 32 + lg * 8) * 2) ^ ((vrow & 7) << 4)));
          acc[n] = __builtin_amdgcn_mfma_f32_16x16x32_bf16(pa, vf, acc[n], 0, 0, 0);
        }
      }
      __builtin_amdgcn_s_setprio(0);
      __builtin_amdgcn_s_barrier();
    }

    float inv_l[4];
#pragma unroll
    for (int r = 0; r < 4; ++r) {
      float v = lsum[r];
      v += __shfl_xor(v, 1);
      v += __shfl_xor(v, 2);
      v += __shfl_xor(v, 4);
      v += __shfl_xor(v, 8);
      inv_l[r] = 1.0f / v;
    }
    const int row0 = qblk * 64 + w * 16 + lg * 4;
    float vv[8][4];
    float ssq[4], dot[4];
#pragma unroll
    for (int r = 0; r < 4; ++r) {
      const u16* pr = qkvb + ((long)(b * SL + row0 + r) * 3072) + 2560 + kvh * 128;
      float sq = 0.f;
#pragma unroll
      for (int n = 0; n < 8; ++n) {
        float t = bf2f(pr[n * 16 + lr]);
        vv[n][r] = t;
        sq += t * t;
      }
      ssq[r] = sq;
    }
#pragma unroll
    for (int r = 0; r < 4; ++r) {
      float sq = ssq[r];
      sq += __shfl_xor(sq, 1);
      sq += __shfl_xor(sq, 2);
      sq += __shfl_xor(sq, 4);
      sq += __shfl_xor(sq, 8);
      ssq[r] = sq;
      float d = 0.f;
#pragma unroll
      for (int n = 0; n < 8; ++n) {
        float yn = acc[n][r] * inv_l[r];
        acc[n][r] = yn;
        d += yn * vv[n][r];
      }
      dot[r] = d;
    }
#pragma unroll
    for (int r = 0; r < 4; ++r) {
      float d = dot[r];
      d += __shfl_xor(d, 1);
      d += __shfl_xor(d, 2);
      d += __shfl_xor(d, 4);
      d += __shfl_xor(d, 8);
      dot[r] = d / fmaxf(ssq[r], 1e-24f);
    }
    u16* yp = yb + ((long)(b * SL + row0)) * DM + h * 128;
#pragma unroll
    for (int n = 0; n < 8; ++n)
#pragma unroll
      for (int r = 0; r < 4; ++r)
        yp[(long)r * DM + n * 16 + lr] = f2bf(acc[n][r] - dot[r] * vv[n][r]);
  }
}

extern "C" void kernel_launch(void* const* d_in, const int* in_sizes, int n_in,
                              void* d_out, int out_size, void* d_ws, size_t ws_size,
                              hipStream_t stream) {
  const float* x  = (const float*)d_in[0];
  const float* Wq = (const float*)d_in[1];
  const float* Wk = (const float*)d_in[2];
  const float* Wv = (const float*)d_in[3];
  const float* Wo = (const float*)d_in[4];
  const float* qg = (const float*)d_in[5];
  float* out = (float*)d_out;

  char* p = (char*)d_ws;
  u16* xb    = (u16*)p;   p += (size_t)4096 * 2048 * 2;
  u16* WT    = (u16*)p;   p += (size_t)3072 * 2048 * 2;
  u16* WoT   = (u16*)p;   p += (size_t)2048 * 2048 * 2;
  u16* qkvb  = (u16*)p;   p += (size_t)4096 * 3072 * 2;
  u16* qbuf  = (u16*)p;   p += (size_t)NB * NH * SL * 128 * 2;
  u16* kbuf  = (u16*)p;   p += (size_t)NB * NKV * SL * 128 * 2;
  u16* vtb   = (u16*)p;   p += (size_t)NB * NKV * 128 * SL * 2;
  u16* yb = xb;  // alias: xb dead after qkv GEMM

  prep<<<6656, 256, 0, stream>>>(x, Wq, Wk, Wv, Wo, xb, WT, WoT);
  gemm_bt<1><<<dim3(16, 24), 256, 0, stream>>>(xb, WT, nullptr, qkvb, 4096, 3072, 2048);
  postqkv<<<4352, 256, 0, stream>>>(qkvb, qg, qbuf, kbuf, vtb);
  attn<<<dim3(16, 32), 256, 0, stream>>>(qbuf, kbuf, vtb, qg, qkvb, yb);
  gemm_bt<0><<<dim3(16, 16), 256, 0, stream>>>(yb, WoT, out, nullptr, 4096, 2048, 2048);
}